// Round 9
// baseline (365.054 us; speedup 1.0000x reference)
//
#include <hip/hip_runtime.h>
#include <hip/hip_fp16.h>

// IGCN forward, round 9: round-8 structure + u16 local column indices
// (halves scatter write-amplification and SpMM col reads) + fp16 emb table
// (feature SpMM gathers 128B rows like the adj layers).
//  - ONE CSR serves feat-SpMM (+bias, degF=degA+1) and all adj-SpMMs.
//  - Cols stored LOCAL to the opposite half: user rows keep item-local idx
//    (<40000), item rows keep user idx (<60000) -> u16.
//  - Scaled state y~ = rsD[row]*y[row] in fp16; adj inner loop is a pure
//    gather-sum; gathered rows un-scale by sqrt(deg).
//  - SpMM: wave = 8 edge-slots x 8 dim-lanes, 16B H8 per lane, unroll 2.

constexpr int kNU = 60000;
constexpr int kNI = 40000;
constexpr int kN  = 100000;
constexpr int kB  = 4096;
constexpr int kNRange = 8, kRangeSz = 12500;
constexpr int kNChunk = 256;

struct alignas(16) H8 { __half2 h[4]; };   // 8 halfs = 16B
struct alignas(8)  H4 { __half2 lo, hi; }; // 4 halfs = 8B

// ---------------- CSR build (ranged, u16 cols) ------------------------------
__global__ void count_deg_ranged(const int4* __restrict__ u4, const int4* __restrict__ i4,
                                 int nV, int* __restrict__ deg) {
  int range = blockIdx.x & (kNRange - 1);
  int chunk = blockIdx.x >> 3;
  int lo = range * kRangeSz, hi = lo + kRangeSz;
  int chunkLen = (nV + kNChunk - 1) / kNChunk;
  int p0 = chunk * chunkLen, p1 = min(nV, p0 + chunkLen);
  for (int p = p0 + (int)threadIdx.x; p < p1; p += 256) {
    int4 uu = u4[p], ii = i4[p];
    if (uu.x >= lo && uu.x < hi) atomicAdd(&deg[uu.x], 1);
    if (uu.y >= lo && uu.y < hi) atomicAdd(&deg[uu.y], 1);
    if (uu.z >= lo && uu.z < hi) atomicAdd(&deg[uu.z], 1);
    if (uu.w >= lo && uu.w < hi) atomicAdd(&deg[uu.w], 1);
    if (ii.x >= lo && ii.x < hi) atomicAdd(&deg[ii.x], 1);
    if (ii.y >= lo && ii.y < hi) atomicAdd(&deg[ii.y], 1);
    if (ii.z >= lo && ii.z < hi) atomicAdd(&deg[ii.z], 1);
    if (ii.w >= lo && ii.w < hi) atomicAdd(&deg[ii.w], 1);
  }
}

__global__ void scatter_ranged(const int4* __restrict__ u4, const int4* __restrict__ i4,
                               int nV, int* __restrict__ cur,
                               unsigned short* __restrict__ colsOut) {
  int range = blockIdx.x & (kNRange - 1);
  int chunk = blockIdx.x >> 3;
  int lo = range * kRangeSz, hi = lo + kRangeSz;
  int chunkLen = (nV + kNChunk - 1) / kNChunk;
  int p0 = chunk * chunkLen, p1 = min(nV, p0 + chunkLen);
  for (int p = p0 + (int)threadIdx.x; p < p1; p += 256) {
    int4 uu = u4[p], ii = i4[p];
    // user rows store item-LOCAL idx; item rows store user idx
    if (uu.x >= lo && uu.x < hi) colsOut[atomicAdd(&cur[uu.x], 1)] = (unsigned short)(ii.x - kNU);
    if (ii.x >= lo && ii.x < hi) colsOut[atomicAdd(&cur[ii.x], 1)] = (unsigned short)uu.x;
    if (uu.y >= lo && uu.y < hi) colsOut[atomicAdd(&cur[uu.y], 1)] = (unsigned short)(ii.y - kNU);
    if (ii.y >= lo && ii.y < hi) colsOut[atomicAdd(&cur[ii.y], 1)] = (unsigned short)uu.y;
    if (uu.z >= lo && uu.z < hi) colsOut[atomicAdd(&cur[uu.z], 1)] = (unsigned short)(ii.z - kNU);
    if (ii.z >= lo && ii.z < hi) colsOut[atomicAdd(&cur[ii.z], 1)] = (unsigned short)uu.z;
    if (uu.w >= lo && uu.w < hi) colsOut[atomicAdd(&cur[uu.w], 1)] = (unsigned short)(ii.w - kNU);
    if (ii.w >= lo && ii.w < hi) colsOut[atomicAdd(&cur[ii.w], 1)] = (unsigned short)uu.w;
  }
}

// ---------------- scan ----------------
constexpr int SCAN_T = 256, SCAN_E = 8, SCAN_CH = SCAN_T * SCAN_E;  // 2048

__global__ void scan_p1(const int* __restrict__ in, int n, int* __restrict__ bsum) {
  __shared__ int lds[SCAN_T];
  int t = threadIdx.x;
  int base = blockIdx.x * SCAN_CH + t * SCAN_E;
  int s = 0;
  #pragma unroll
  for (int k = 0; k < SCAN_E; ++k) { int i = base + k; if (i < n) s += in[i]; }
  lds[t] = s; __syncthreads();
  for (int off = SCAN_T / 2; off; off >>= 1) {
    if (t < off) lds[t] += lds[t + off];
    __syncthreads();
  }
  if (t == 0) bsum[blockIdx.x] = lds[0];
}

__global__ void scan_p2(int* bsum, int nb) {
  if (threadIdx.x == 0 && blockIdx.x == 0) {
    int run = 0;
    for (int i = 0; i < nb; ++i) { int v = bsum[i]; bsum[i] = run; run += v; }
  }
}

__global__ void scan_p3(const int* __restrict__ in, int n, int ntot,
                        const int* __restrict__ bsum,
                        int* __restrict__ out, int* __restrict__ cur) {
  __shared__ int lds[SCAN_T];
  int t = threadIdx.x;
  int base = blockIdx.x * SCAN_CH + t * SCAN_E;
  int v[SCAN_E]; int s = 0;
  #pragma unroll
  for (int k = 0; k < SCAN_E; ++k) { int i = base + k; v[k] = (i < n) ? in[i] : 0; s += v[k]; }
  lds[t] = s; __syncthreads();
  for (int off = 1; off < SCAN_T; off <<= 1) {
    int x = (t >= off) ? lds[t - off] : 0;
    __syncthreads();
    lds[t] += x;
    __syncthreads();
  }
  int pre = lds[t] - s + bsum[blockIdx.x];
  #pragma unroll
  for (int k = 0; k < SCAN_E; ++k) {
    int i = base + k;
    if (i < n) { out[i] = pre; cur[i] = pre; pre += v[k]; }
  }
  if (blockIdx.x == 0 && t == 0) out[n] = ntot;
}

__global__ void make_rsd(const int* __restrict__ deg, float* __restrict__ rsDg, int n) {
  int i = blockIdx.x * blockDim.x + threadIdx.x;
  if (i < n) { int d = deg[i]; rsDg[i] = d > 0 ? rsqrtf((float)d) : 1.f; }
}

// ---------------- emb fp32 -> fp16 ------------------------------------------
__global__ void emb_to_h(const float4* __restrict__ in, H4* __restrict__ outp, int n) {
  int i = blockIdx.x * 256 + threadIdx.x;
  if (i < n) {
    float4 v = in[i];
    float2 lo = {v.x, v.y}, hi = {v.z, v.w};
    H4 o; o.lo = __float22half2_rn(lo); o.hi = __float22half2_rn(hi);
    outp[i] = o;
  }
}

// ---------------- feat SpMM, all nodes: fp16 emb gather -> fp16 y~0 ---------
// wave = 8 edge-slots x 8 dim-lanes (16B H8), unroll 2.
__global__ void spmm_feat_all(const int* __restrict__ rs, const unsigned short* __restrict__ cols,
                              const H8* __restrict__ emb16, const float* __restrict__ rsDg,
                              H8* __restrict__ hU, H8* __restrict__ hI) {
  int row = blockIdx.x * 4 + (threadIdx.x >> 6);
  if (row >= kN) return;
  int lane = threadIdx.x & 63, g = lane >> 3, q = lane & 7;
  int s = rs[row], e = rs[row + 1];
  int base = (row < kNU) ? kNU : 0;   // emb idx = base + local col
  float a[8];
  #pragma unroll
  for (int k = 0; k < 8; ++k) a[k] = 0.f;
  int j = s + g;
  for (; j + 8 < e; j += 16) {
    int c0 = cols[j], c1 = cols[j + 8];
    H8 v0 = emb16[(long)(base + c0) * 8 + q];
    H8 v1 = emb16[(long)(base + c1) * 8 + q];
    #pragma unroll
    for (int k = 0; k < 4; ++k) {
      float2 f0 = __half22float2(v0.h[k]);
      float2 f1 = __half22float2(v1.h[k]);
      a[2 * k]     += f0.x + f1.x;
      a[2 * k + 1] += f0.y + f1.y;
    }
  }
  if (j < e) {
    int c = cols[j];
    H8 v = emb16[(long)(base + c) * 8 + q];
    #pragma unroll
    for (int k = 0; k < 4; ++k) {
      float2 f = __half22float2(v.h[k]);
      a[2 * k] += f.x; a[2 * k + 1] += f.y;
    }
  }
  #pragma unroll
  for (int m = 8; m <= 32; m <<= 1) {
    #pragma unroll
    for (int k = 0; k < 8; ++k) a[k] += __shfl_xor(a[k], m, 64);
  }
  if (g == 0) {
    H8 bv = emb16[(long)((row < kNU) ? 100000 : 100001) * 8 + q];
    float sc = rsDg[row] / (float)(e - s + 1);
    H8 o;
    #pragma unroll
    for (int k = 0; k < 4; ++k) {
      float2 bf = __half22float2(bv.h[k]);
      float2 f = {(a[2 * k] + bf.x) * sc, (a[2 * k + 1] + bf.y) * sc};
      o.h[k] = __float22half2_rn(f);
    }
    H8* dst = (row < kNU) ? (hU + (long)row * 8) : (hI + (long)(row - kNU) * 8);
    dst[q] = o;
  }
}

// ---------------- adj SpMM, all nodes: fp16 gather-sum -> fp16 --------------
__global__ void spmm_adj_all(const int* __restrict__ rs, const unsigned short* __restrict__ cols,
                             const float* __restrict__ rsDg,
                             const H8* __restrict__ inU, const H8* __restrict__ inI,
                             H8* __restrict__ outU, H8* __restrict__ outI) {
  int row = blockIdx.x * 4 + (threadIdx.x >> 6);
  if (row >= kN) return;
  int lane = threadIdx.x & 63, g = lane >> 3, q = lane & 7;
  const H8* src = (row < kNU) ? inI : inU;   // cols are local to opposite half
  int s = rs[row], e = rs[row + 1];
  float a[8];
  #pragma unroll
  for (int k = 0; k < 8; ++k) a[k] = 0.f;
  int j = s + g;
  for (; j + 8 < e; j += 16) {
    int c0 = cols[j], c1 = cols[j + 8];
    H8 v0 = src[(long)c0 * 8 + q];
    H8 v1 = src[(long)c1 * 8 + q];
    #pragma unroll
    for (int k = 0; k < 4; ++k) {
      float2 f0 = __half22float2(v0.h[k]);
      float2 f1 = __half22float2(v1.h[k]);
      a[2 * k]     += f0.x + f1.x;
      a[2 * k + 1] += f0.y + f1.y;
    }
  }
  if (j < e) {
    int c = cols[j];
    H8 v = src[(long)c * 8 + q];
    #pragma unroll
    for (int k = 0; k < 4; ++k) {
      float2 f = __half22float2(v.h[k]);
      a[2 * k] += f.x; a[2 * k + 1] += f.y;
    }
  }
  #pragma unroll
  for (int m = 8; m <= 32; m <<= 1) {
    #pragma unroll
    for (int k = 0; k < 8; ++k) a[k] += __shfl_xor(a[k], m, 64);
  }
  if (g == 0) {
    float w = rsDg[row]; w = w * w;   // = 1/deg (deg>0); empty row -> 0 sum
    H8 o;
    #pragma unroll
    for (int k = 0; k < 4; ++k) {
      float2 f = {a[2 * k] * w, a[2 * k + 1] * w};
      o.h[k] = __float22half2_rn(f);
    }
    H8* dst = (row < kNU) ? (outU + (long)row * 8) : (outI + (long)(row - kNU) * 8);
    dst[q] = o;
  }
}

// ---------------- gathered-row accumulation (un-scale by sqrt(deg)) ---------
__global__ void acc_gather_h(const H8* __restrict__ hU, const H8* __restrict__ hI,
                             const int* __restrict__ deg,
                             const int* __restrict__ users, const int* __restrict__ pos,
                             const int* __restrict__ neg, float4* __restrict__ out, int add) {
  int gI = blockIdx.x * blockDim.x + threadIdx.x;
  if (gI >= 3 * kB * 8) return;
  int slot = gI >> 3, q = gI & 7;
  int which = slot >> 12, b = slot & (kB - 1);
  int node = which == 0 ? users[b] : (which == 1 ? pos[b] + kNU : neg[b] + kNU);
  H8 v = (node < kNU) ? hU[(long)node * 8 + q] : hI[(long)(node - kNU) * 8 + q];
  float sq = sqrtf((float)max(deg[node], 1));
  float2 f0 = __half22float2(v.h[0]), f1 = __half22float2(v.h[1]);
  float2 f2 = __half22float2(v.h[2]), f3 = __half22float2(v.h[3]);
  float4 r0 = {f0.x * sq, f0.y * sq, f1.x * sq, f1.y * sq};
  float4 r1 = {f2.x * sq, f2.y * sq, f3.x * sq, f3.y * sq};
  long o0 = (long)slot * 16 + q * 2;
  if (add) {
    float4 a0 = out[o0], a1 = out[o0 + 1];
    r0.x += a0.x; r0.y += a0.y; r0.z += a0.z; r0.w += a0.w;
    r1.x += a1.x; r1.y += a1.y; r1.z += a1.z; r1.w += a1.w;
  }
  out[o0] = r0; out[o0 + 1] = r1;
}

// ---------------- layer 3 restricted + /4 + per-row L2 ----------------------
__global__ void layer3_fin(const int* __restrict__ rs, const unsigned short* __restrict__ cols,
                           const float* __restrict__ rsDg,
                           const H8* __restrict__ hU, const H8* __restrict__ hI,
                           const int* __restrict__ users, const int* __restrict__ pos,
                           const int* __restrict__ neg,
                           float4* __restrict__ out, float* __restrict__ l2part) {
  int slot = blockIdx.x * 4 + (threadIdx.x >> 6);
  if (slot >= 3 * kB) return;
  int lane = threadIdx.x & 63, g = lane >> 3, q = lane & 7;
  int which = slot >> 12, b = slot & (kB - 1);
  int node = which == 0 ? users[b] : (which == 1 ? pos[b] + kNU : neg[b] + kNU);
  const H8* src = (node < kNU) ? hI : hU;
  int s = rs[node], e = rs[node + 1];
  float a[8];
  #pragma unroll
  for (int k = 0; k < 8; ++k) a[k] = 0.f;
  int j = s + g;
  for (; j + 8 < e; j += 16) {
    int c0 = cols[j], c1 = cols[j + 8];
    H8 v0 = src[(long)c0 * 8 + q];
    H8 v1 = src[(long)c1 * 8 + q];
    #pragma unroll
    for (int k = 0; k < 4; ++k) {
      float2 f0 = __half22float2(v0.h[k]);
      float2 f1 = __half22float2(v1.h[k]);
      a[2 * k]     += f0.x + f1.x;
      a[2 * k + 1] += f0.y + f1.y;
    }
  }
  if (j < e) {
    int c = cols[j];
    H8 v = src[(long)c * 8 + q];
    #pragma unroll
    for (int k = 0; k < 4; ++k) {
      float2 f = __half22float2(v.h[k]);
      a[2 * k] += f.x; a[2 * k + 1] += f.y;
    }
  }
  #pragma unroll
  for (int m = 8; m <= 32; m <<= 1) {
    #pragma unroll
    for (int k = 0; k < 8; ++k) a[k] += __shfl_xor(a[k], m, 64);
  }
  float t = 0.f;
  if (g == 0) {
    float sr = rsDg[node];   // y3 = rsDg * sum(in~)
    long o0 = (long)slot * 16 + q * 2;
    float4 a0 = out[o0], a1 = out[o0 + 1];
    float4 r0 = {(a0.x + a[0] * sr) * 0.25f, (a0.y + a[1] * sr) * 0.25f,
                 (a0.z + a[2] * sr) * 0.25f, (a0.w + a[3] * sr) * 0.25f};
    float4 r1 = {(a1.x + a[4] * sr) * 0.25f, (a1.y + a[5] * sr) * 0.25f,
                 (a1.z + a[6] * sr) * 0.25f, (a1.w + a[7] * sr) * 0.25f};
    out[o0] = r0; out[o0 + 1] = r1;
    t = r0.x * r0.x + r0.y * r0.y + r0.z * r0.z + r0.w * r0.w
      + r1.x * r1.x + r1.y * r1.y + r1.z * r1.z + r1.w * r1.w;
  }
  #pragma unroll
  for (int m = 1; m <= 4; m <<= 1) t += __shfl_xor(t, m, 64);
  if (lane == 0) l2part[slot] = t;
}

__global__ void l2_final(const float* __restrict__ l2part, float* __restrict__ outl2) {
  int b = blockIdx.x * blockDim.x + threadIdx.x;
  if (b < kB) outl2[b] = l2part[b] + l2part[kB + b] + l2part[2 * kB + b];
}

extern "C" void kernel_launch(void* const* d_in, const int* in_sizes, int n_in,
                              void* d_out, int out_size, void* d_ws, size_t ws_size,
                              hipStream_t stream) {
  const float* emb  = (const float*)d_in[0];
  const int*   arow = (const int*)d_in[3];
  const int*   users= (const int*)d_in[5];
  const int*   pos  = (const int*)d_in[6];
  const int*   neg  = (const int*)d_in[7];
  const int neA = in_sizes[3];              // 2,000,000
  const int nP  = neA / 2;                  // 1,000,000 pairs
  const int nV  = nP / 4;
  const int4* u4 = (const int4*)arow;
  const int4* i4 = (const int4*)(arow + nP);

  char* ws = (char*)d_ws;
  int*            degA   = (int*)(ws + 0);            // 400,000
  int*            rsArr  = (int*)(ws + 400000);       // 400,004 (pad to 400128)
  int*            cur    = (int*)(ws + 800128);       // 400,000
  float*          rsDg   = (float*)(ws + 1200128);    // 400,000
  float*          l2part = (float*)(ws + 1600128);    // 49,152
  int*            bsum   = (int*)(ws + 1649280);      // 1,024
  unsigned short* colA   = (unsigned short*)(ws + 1650304);  // 4,000,000
  __half*         emb16  = (__half*)(ws + 5650304);   // 12,800,256 (pad to 12800320)
  __half*         hU0    = (__half*)(ws + 18450624);  // 7,680,000
  __half*         hU1    = (__half*)(ws + 26130624);  // 7,680,000
  __half*         hI0    = (__half*)(ws + 33810624);  // 5,120,000
  __half*         hI1    = (__half*)(ws + 38930624);  // 5,120,000 -> end 44,050,624

  float* out = (float*)d_out;
  const int NB = (kN + SCAN_CH - 1) / SCAN_CH;  // 49

  hipMemsetAsync(degA, 0, 400000, stream);
  count_deg_ranged<<<kNRange * kNChunk, 256, 0, stream>>>(u4, i4, nV, degA);
  scan_p1<<<NB, SCAN_T, 0, stream>>>(degA, kN, bsum);
  scan_p2<<<1, 64, 0, stream>>>(bsum, NB);
  scan_p3<<<NB, SCAN_T, 0, stream>>>(degA, kN, neA, bsum, rsArr, cur);
  make_rsd<<<(kN + 255) / 256, 256, 0, stream>>>(degA, rsDg, kN);
  const int nE16 = 100002 * 16;   // float4 elements in emb
  emb_to_h<<<(nE16 + 255) / 256, 256, 0, stream>>>((const float4*)emb, (H4*)emb16, nE16);
  scatter_ranged<<<kNRange * kNChunk, 256, 0, stream>>>(u4, i4, nV, cur, colA);

  const int GN = (kN + 3) / 4;   // 25000 blocks, 4 rows each

  // feature SpMM -> fp16 scaled state y~0
  spmm_feat_all<<<GN, 256, 0, stream>>>(rsArr, colA, (const H8*)emb16, rsDg,
                                        (H8*)hU0, (H8*)hI0);
  acc_gather_h<<<(3 * kB * 8 + 255) / 256, 256, 0, stream>>>((const H8*)hU0, (const H8*)hI0,
      degA, users, pos, neg, (float4*)out, 0);

  // layer 1: (hU0,hI0) -> (hU1,hI1)
  spmm_adj_all<<<GN, 256, 0, stream>>>(rsArr, colA, rsDg, (const H8*)hU0, (const H8*)hI0,
                                       (H8*)hU1, (H8*)hI1);
  acc_gather_h<<<(3 * kB * 8 + 255) / 256, 256, 0, stream>>>((const H8*)hU1, (const H8*)hI1,
      degA, users, pos, neg, (float4*)out, 1);

  // layer 2: (hU1,hI1) -> (hU0,hI0)
  spmm_adj_all<<<GN, 256, 0, stream>>>(rsArr, colA, rsDg, (const H8*)hU1, (const H8*)hI1,
                                       (H8*)hU0, (H8*)hI0);
  acc_gather_h<<<(3 * kB * 8 + 255) / 256, 256, 0, stream>>>((const H8*)hU0, (const H8*)hI0,
      degA, users, pos, neg, (float4*)out, 1);

  // layer 3 restricted + epilogue (reads layer-2 state)
  layer3_fin<<<(3 * kB + 3) / 4, 256, 0, stream>>>(rsArr, colA, rsDg, (const H8*)hU0,
                                                   (const H8*)hI0, users, pos, neg,
                                                   (float4*)out, l2part);
  l2_final<<<(kB + 255) / 256, 256, 0, stream>>>(l2part, out + 3 * kB * 64);
}